// Round 4
// baseline (467.536 us; speedup 1.0000x reference)
//
#include <hip/hip_runtime.h>
#include <hip/hip_bf16.h>

#define NN 100000
#define EE 1600000
#define RR 8
#define NBKT 196          // ceil(NN/512) buckets of 512 nodes
#define ACHUNK 8192       // edges per partition block
#define CAP 10240         // per-bucket capacity: mean 8192, sd ~90 -> 22 sigma headroom
#define NB_NODES ((NN + 63) / 64)   // 1563 gemm blocks

typedef __attribute__((ext_vector_type(8))) short bf16x8;
typedef __attribute__((ext_vector_type(4))) float f32x4;

__device__ __forceinline__ unsigned short f2bf(float v) {
    __hip_bfloat16 h = __float2bfloat16(v);
    return *reinterpret_cast<unsigned short*>(&h);
}
__device__ __forceinline__ float bf2f(unsigned short u) {
    unsigned x = (unsigned)u << 16;
    return __uint_as_float(x);
}

// ---------- prep device helpers ----------
template<int IN_DIM>
__device__ __forceinline__ void wt_frag_dev(const float* __restrict__ W,
                                            unsigned short* __restrict__ Wf, int r) {
    constexpr int KSTEPS = IN_DIM / 32;
    for (int i = threadIdx.x; i < IN_DIM * 64; i += 256) {
        int k = i >> 6, o = i & 63;
        int ks = k >> 5, quad = (k >> 3) & 3, j = k & 7;
        int tl = o >> 4, l16 = o & 15;
        int lane = quad * 16 + l16;
        size_t idx = ((((size_t)r * KSTEPS + ks) * 4 + tl) * 64 + lane) * 8 + j;
        Wf[idx] = f2bf(W[((size_t)r * IN_DIM + k) * 64 + o]);
    }
}

template<int IN_DIM>
__device__ __forceinline__ void wqk_frag_dev(const float* __restrict__ W,
        const float* __restrict__ q, const float* __restrict__ k,
        unsigned short* __restrict__ Sf, int blk, int nb) {
    for (int i = blk * 256 + threadIdx.x; i < IN_DIM * 16; i += nb * 256) {
        int j = i & 7, lane = (i >> 3) & 63, ks = i >> 9;
        int col = lane & 15, quad = lane >> 4;
        int kd = ks * 32 + quad * 8 + j;
        const float* v = (col < 8) ? q : k;
        int r = (col < 8) ? col : col - 8;
        float s = 0.f;
        #pragma unroll
        for (int o = 0; o < 64; o++) s += W[((size_t)r * IN_DIM + kd) * 64 + o] * v[o];
        Sf[i] = f2bf(s);
    }
}

// one kernel: all weight prep + all zero-init
__global__ __launch_bounds__(256)
void prep(const float* __restrict__ W1, const float* __restrict__ q1, const float* __restrict__ k1,
          const float* __restrict__ W2, const float* __restrict__ q2, const float* __restrict__ k2,
          unsigned short* __restrict__ Wf1, unsigned short* __restrict__ Wf2,
          unsigned short* __restrict__ Sf1, unsigned short* __restrict__ Sf2,
          unsigned* __restrict__ bcnt, float* __restrict__ stats)
{
    int b = blockIdx.x;
    if (b < 8)        wt_frag_dev<128>(W1, Wf1, b);
    else if (b < 16)  wt_frag_dev<64>(W2, Wf2, b - 8);
    else if (b < 20)  wqk_frag_dev<128>(W1, q1, k1, Sf1, b - 16, 4);
    else if (b == 20) wqk_frag_dev<64>(W2, q2, k2, Sf2, 0, 1);
    else {
        int t = threadIdx.x;
        if (t < NBKT) bcnt[t] = 0;
        if (t < 128) stats[t] = 0.f;
    }
}

// ---------------- bucketed CSR build (single-pass: fixed-capacity buckets) ----------------
__global__ __launch_bounds__(256)
void part_scatter(const int* __restrict__ src, const int* __restrict__ dst,
                  const int* __restrict__ et, unsigned* __restrict__ bcnt,
                  unsigned* __restrict__ tmp) {
    __shared__ unsigned h[NBKT], base[NBKT];
    int t = threadIdx.x;
    for (int i = t; i < NBKT; i += 256) h[i] = 0;
    __syncthreads();
    int e0 = blockIdx.x * ACHUNK;
    for (int i = t; i < ACHUNK; i += 256) {
        int e = e0 + i;
        if (e < EE) atomicAdd(&h[((unsigned)dst[e]) >> 9], 1u);
    }
    __syncthreads();
    for (int i = t; i < NBKT; i += 256) {
        base[i] = (unsigned)i * CAP + (h[i] ? atomicAdd(&bcnt[i], h[i]) : 0u);
        h[i] = 0;
    }
    __syncthreads();
    for (int i = t; i < ACHUNK; i += 256) {
        int e = e0 + i;
        if (e < EE) {
            unsigned d = (unsigned)dst[e];
            unsigned bk = d >> 9;
            unsigned off = atomicAdd(&h[bk], 1u);
            unsigned pos = base[bk] + off;
            if (pos < (bk + 1u) * CAP) {   // statistically unreachable clamp
                unsigned val = ((d & 511u) << 23) | ((unsigned)et[e] << 20) | (unsigned)src[e];
                tmp[pos] = val;
            }
        }
    }
}

__global__ __launch_bounds__(512)
void bucket_csr(const unsigned* __restrict__ bcnt, const unsigned* __restrict__ tmp,
                unsigned* __restrict__ rowstart, unsigned* __restrict__ rowdeg,
                unsigned* __restrict__ pk) {
    __shared__ unsigned lcnt[512], lscan[512], lrs[512];
    int b = blockIdx.x, t = threadIdx.x;
    unsigned ebeg = (unsigned)b * CAP;
    unsigned cnt = min(bcnt[b], (unsigned)CAP);
    unsigned eend = ebeg + cnt;
    lcnt[t] = 0;
    __syncthreads();
    for (unsigned i = ebeg + t; i < eend; i += 512)
        atomicAdd(&lcnt[tmp[i] >> 23], 1u);
    __syncthreads();
    unsigned v = lcnt[t];
    lscan[t] = v;
    __syncthreads();
    for (int off = 1; off < 512; off <<= 1) {
        unsigned u = (t >= off) ? lscan[t - off] : 0u;
        __syncthreads();
        lscan[t] += u;
        __syncthreads();
    }
    unsigned excl = lscan[t] - v;
    lrs[t] = ebeg + excl;
    int node = b * 512 + t;
    if (node < NN) { rowstart[node] = ebeg + excl; rowdeg[node] = v; }
    lcnt[t] = 0;
    __syncthreads();
    for (unsigned i = ebeg + t; i < eend; i += 512) {
        unsigned val = tmp[i];
        unsigned d = val >> 23;
        unsigned pos = lrs[d] + atomicAdd(&lcnt[d], 1u);
        pk[pos] = val & 0x7FFFFFu;
    }
}

// ---------- MFMA GEMM + per-block sk-max (PLAIN stores, no atomics:
// R3 showed gemm 84% stall at 7% MfmaUtil — 1563 same-address atomicMax chains
// were the prime suspect; per-block gmax has zero contention) ----------
template<int IN_DIM, bool BF16IN>
__global__ __launch_bounds__(256)
void gemm_mfma(const void* __restrict__ xv, const unsigned short* __restrict__ Wf,
               const unsigned short* __restrict__ Sf,
               unsigned short* __restrict__ xw,
               float* __restrict__ sq, float* __restrict__ sk,
               float* __restrict__ gmax)
{
    constexpr int KSTEPS = IN_DIM / 32;
    constexpr int NB = IN_DIM / 8;
    __shared__ unsigned short xl[64 * IN_DIM];
    __shared__ float smax[4][8];

    const int n0 = blockIdx.x * 64;
    const int t = threadIdx.x;
    const int wave = t >> 6, lane = t & 63;
    const int quad = lane >> 4, l16 = lane & 15;

    for (int c = t; c < 64 * IN_DIM / 4; c += 256) {
        int row = c / (IN_DIM / 4), kc = (c % (IN_DIM / 4)) * 4;
        int gr = n0 + row;
        ushort4 u = make_ushort4(0, 0, 0, 0);
        if constexpr (BF16IN) {
            if (gr < NN) u = *(const ushort4*)((const unsigned short*)xv + (size_t)gr * IN_DIM + kc);
        } else {
            if (gr < NN) {
                float4 v = *(const float4*)((const float*)xv + (size_t)gr * IN_DIM + kc);
                u.x = f2bf(v.x); u.y = f2bf(v.y); u.z = f2bf(v.z); u.w = f2bf(v.w);
            }
        }
        int b = kc >> 3;
        *(ushort4*)&xl[row * IN_DIM + ((b ^ (row & (NB - 1))) << 3) + (kc & 7)] = u;
    }
    __syncthreads();

    bf16x8 afr[KSTEPS];
    const int arow = wave * 16 + l16;
    #pragma unroll
    for (int ks = 0; ks < KSTEPS; ks++) {
        int b = ks * 4 + quad;
        afr[ks] = *(const bf16x8*)&xl[arow * IN_DIM + ((b ^ (arow & (NB - 1))) << 3)];
    }

    // ---- sq/sk for ALL relations via one MFMA chain + per-block sk max ----
    {
        f32x4 accs = {0.f, 0.f, 0.f, 0.f};
        #pragma unroll
        for (int ks = 0; ks < KSTEPS; ks++) {
            bf16x8 sfr = *(const bf16x8*)&Sf[(ks * 64 + lane) * 8];
            accs = __builtin_amdgcn_mfma_f32_16x16x32_bf16(afr[ks], sfr, accs, 0, 0, 0);
        }
        float pm = -1e30f;
        #pragma unroll
        for (int reg = 0; reg < 4; reg++) {
            int grow = n0 + wave * 16 + quad * 4 + reg;
            if (grow < NN) {
                if (l16 < 8) sq[(size_t)l16 * NN + grow] = accs[reg];
                else { sk[(size_t)(l16 - 8) * NN + grow] = accs[reg]; pm = fmaxf(pm, accs[reg]); }
            }
        }
        pm = fmaxf(pm, __shfl_xor(pm, 16, 64));
        pm = fmaxf(pm, __shfl_xor(pm, 32, 64));
        if (quad == 0 && l16 >= 8) smax[wave][l16 - 8] = pm;
    }
    __syncthreads();
    if (t < 8) {
        float v = fmaxf(fmaxf(smax[0][t], smax[1][t]), fmaxf(smax[2][t], smax[3][t]));
        gmax[blockIdx.x * 8 + t] = v;                 // plain store, no RMW
    }

    #pragma unroll 1
    for (int r = 0; r < RR; r++) {
        bf16x8 bfr[KSTEPS][4];
        const unsigned short* Wb = Wf + (((size_t)r * KSTEPS) * 4) * 64 * 8 + lane * 8;
        #pragma unroll
        for (int ks = 0; ks < KSTEPS; ks++)
            #pragma unroll
            for (int tl = 0; tl < 4; tl++)
                bfr[ks][tl] = *(const bf16x8*)(Wb + ((ks * 4 + tl) * 64) * 8);

        f32x4 acc[4] = {{0.f,0.f,0.f,0.f},{0.f,0.f,0.f,0.f},{0.f,0.f,0.f,0.f},{0.f,0.f,0.f,0.f}};
        #pragma unroll
        for (int ks = 0; ks < KSTEPS; ks++)
            #pragma unroll
            for (int tl = 0; tl < 4; tl++)
                acc[tl] = __builtin_amdgcn_mfma_f32_16x16x32_bf16(afr[ks], bfr[ks][tl], acc[tl], 0, 0, 0);

        const size_t rbase = (size_t)r * NN;
        #pragma unroll
        for (int reg = 0; reg < 4; reg++) {
            int grow = n0 + wave * 16 + quad * 4 + reg;
            if (grow < NN) {
                ushort4 u;
                u.x = f2bf(acc[0][reg]); u.y = f2bf(acc[1][reg]);
                u.z = f2bf(acc[2][reg]); u.w = f2bf(acc[3][reg]);
                *(ushort4*)(xw + (rbase + grow) * 64 + l16 * 4) = u;
            }
        }
    }
}

// ---------- tiny tree-reduce: gmax[1563][8] -> mxk[8] (one 64-lane wave) ----------
__global__ void max_reduce(const float* __restrict__ gmax, float* __restrict__ mxk) {
    int L = threadIdx.x;
    int r = L & 7;
    float m = -1e30f;
    for (int b = L >> 3; b < NB_NODES; b += 8)
        m = fmaxf(m, gmax[b * 8 + r]);
    m = fmaxf(m, __shfl_xor(m, 8, 64));
    m = fmaxf(m, __shfl_xor(m, 16, 64));
    m = fmaxf(m, __shfl_xor(m, 32, 64));
    if (L < 8) mxk[L] = m;
}

// ---------- Fused per-node softmax + aggregate ----------
// R0/R3-proven shfl-broadcast gather, unrolled to 8 edges / 2 independent
// gathers in flight (pure registers — no LDS staging, no wave_barrier).
// sq held in lane (lane&7) and fetched per-edge via one shfl.
// LAYER==1 writes bf16 (gemm converts to bf16 anyway -> numerically identical).
template<int LAYER>
__global__ __launch_bounds__(256)
void node_aggregate(const unsigned* __restrict__ rowstart, const unsigned* __restrict__ rowdeg,
                    const unsigned* __restrict__ pk,
                    const float* __restrict__ sq, const float* __restrict__ sk,
                    const float* __restrict__ mxk,
                    const unsigned short* __restrict__ xw, const float* __restrict__ b,
                    void* __restrict__ outv)
{
    const int node = blockIdx.x * 4 + (threadIdx.x >> 6);
    const int lane = threadIdx.x & 63;
    const int g = lane >> 4, c16 = lane & 15;
    const unsigned beg = rowstart[node];
    const unsigned deg = rowdeg[node];
    const unsigned end = beg + deg;

    const float sqreg = sq[(size_t)(lane & 7) * NN + node];
    float tmx = sqreg + mxk[lane & 7];
    tmx = fmaxf(tmx, __shfl_xor(tmx, 1, 64));
    tmx = fmaxf(tmx, __shfl_xor(tmx, 2, 64));
    tmx = fmaxf(tmx, __shfl_xor(tmx, 4, 64));
    const float m = tmx > 0.f ? tmx : 0.2f * tmx;   // leaky is monotonic: bound survives

    float a0 = 0.f, a1 = 0.f, a2 = 0.f, a3 = 0.f, den = 0.f;
    for (unsigned c0 = beg; c0 < end; c0 += 64) {
        unsigned i = c0 + lane;
        unsigned p = 0;
        if (i < end) p = pk[i];
        unsigned r = p >> 20;
        unsigned rowidx = r * NN + (p & 0xFFFFFu);   // pads -> row 0 (harmless)
        float skv = sk[rowidx];
        float sqv_e = __shfl(sqreg, (int)r, 64);     // uniform flow: sources active
        float a = sqv_e + skv;
        a = a > 0.f ? a : 0.2f * a;
        float w = __expf(a - m);
        if (i >= end) w = 0.f;
        den += w;
        int cnt8 = ((int)min(64u, end - c0) + 7) & ~7;   // pad lanes have w=0
        for (int j = 0; j < cnt8; j += 8) {
            float    w0 = __shfl(w, j + g, 64);
            unsigned r0 = (unsigned)__shfl((int)rowidx, j + g, 64);
            float    w1 = __shfl(w, j + 4 + g, 64);
            unsigned r1 = (unsigned)__shfl((int)rowidx, j + 4 + g, 64);
            ushort4 v0 = *(const ushort4*)(xw + (size_t)r0 * 64 + c16 * 4);
            ushort4 v1 = *(const ushort4*)(xw + (size_t)r1 * 64 + c16 * 4);
            a0 += w0 * bf2f(v0.x) + w1 * bf2f(v1.x);
            a1 += w0 * bf2f(v0.y) + w1 * bf2f(v1.y);
            a2 += w0 * bf2f(v0.z) + w1 * bf2f(v1.z);
            a3 += w0 * bf2f(v0.w) + w1 * bf2f(v1.w);
        }
    }
    #pragma unroll
    for (int off = 32; off >= 1; off >>= 1)
        den += __shfl_xor(den, off, 64);
    // combine the 4 edge-subgroups: lanes L, L^16, L^32, L^48 hold same channels
    a0 += __shfl_xor(a0, 16, 64); a0 += __shfl_xor(a0, 32, 64);
    a1 += __shfl_xor(a1, 16, 64); a1 += __shfl_xor(a1, 32, 64);
    a2 += __shfl_xor(a2, 16, 64); a2 += __shfl_xor(a2, 32, 64);
    a3 += __shfl_xor(a3, 16, 64); a3 += __shfl_xor(a3, 32, 64);

    float accg = (g == 0) ? a0 : (g == 1) ? a1 : (g == 2) ? a2 : a3;
    float res = (deg > 0) ? accg / (den + 1e-16f) : 0.f;
    int c = g * 16 + c16;
    if constexpr (LAYER == 1) {
        res += b[c];
        res = res > 0.f ? res : 0.f;
        ((unsigned short*)outv)[(size_t)node * 64 + c] = f2bf(res);
    } else {
        ((float*)outv)[(size_t)node * 64 + c] = res;
    }
}

// ---------------- BatchNorm (separate stats kernel: 512 blocks -> 65k atomics, R0-proven) ----
__global__ __launch_bounds__(256)
void bn_stats(const float* __restrict__ x, float* __restrict__ stats)
{
    int c = threadIdx.x & 63;
    int w = threadIdx.x >> 6;
    float s = 0.f, s2 = 0.f;
    for (int row = blockIdx.x * 4 + w; row < NN; row += gridDim.x * 4) {
        float v = x[(size_t)row * 64 + c];
        s += v; s2 += v * v;
    }
    __shared__ float ls[4][64], ls2[4][64];
    ls[w][c] = s; ls2[w][c] = s2;
    __syncthreads();
    if (threadIdx.x < 64) {
        atomicAdd(&stats[c],      ls[0][c] + ls[1][c] + ls[2][c] + ls[3][c]);
        atomicAdd(&stats[64 + c], ls2[0][c] + ls2[1][c] + ls2[2][c] + ls2[3][c]);
    }
}

__global__ __launch_bounds__(256)
void bn_apply(float* __restrict__ x, const float* __restrict__ stats,
              const float* __restrict__ gamma, const float* __restrict__ beta)
{
    int i = blockIdx.x * 256 + threadIdx.x;
    if (i >= NN * 64) return;
    int c = i & 63;
    float mean = stats[c] * (1.f / NN);
    float var  = stats[64 + c] * (1.f / NN) - mean * mean;
    float sc   = rsqrtf(var + 1e-5f) * gamma[c];
    float v = (x[i] - mean) * sc + beta[c];
    x[i] = v > 0.f ? v : 0.01f * v;
}

// ---------------- driver ----------------
extern "C" void kernel_launch(void* const* d_in, const int* in_sizes, int n_in,
                              void* d_out, int out_size, void* d_ws, size_t ws_size,
                              hipStream_t stream)
{
    const float* x0 = (const float*)d_in[0];
    const int*   ei = (const int*)d_in[1];
    const int*   et = (const int*)d_in[2];
    const float* W1 = (const float*)d_in[3];
    const float* q1 = (const float*)d_in[4];
    const float* k1 = (const float*)d_in[5];
    const float* b1 = (const float*)d_in[6];
    const float* W2 = (const float*)d_in[7];
    const float* q2 = (const float*)d_in[8];
    const float* k2 = (const float*)d_in[9];
    const float* gamma = (const float*)d_in[11];
    const float* beta  = (const float*)d_in[12];
    const int* src = ei;
    const int* dst = ei + EE;
    float* out = (float*)d_out;

    char* base = (char*)d_ws;
    size_t off = 0;
    auto take = [&](size_t bytes) -> char* {
        char* p = base + off;
        off = (off + bytes + 255) & ~(size_t)255;
        return p;
    };
    float*    sq       = (float*)take((size_t)RR * NN * 4);
    float*    sk       = (float*)take((size_t)RR * NN * 4);
    unsigned* rowstart = (unsigned*)take((size_t)NN * 4);
    unsigned* rowdeg   = (unsigned*)take((size_t)NN * 4);
    unsigned* bcnt     = (unsigned*)take((size_t)NBKT * 4);
    unsigned* tmp      = (unsigned*)take((size_t)NBKT * CAP * 4);
    unsigned* pk       = (unsigned*)take((size_t)NBKT * CAP * 4);
    unsigned short* x1 = (unsigned short*)take((size_t)NN * 64 * 2);
    float*    stats    = (float*)take(512);
    float*    gmax     = (float*)take((size_t)NB_NODES * 8 * 4);
    float*    mxk1     = (float*)take(RR * 4);
    float*    mxk2     = (float*)take(RR * 4);
    unsigned short* Wf1 = (unsigned short*)take((size_t)RR * 128 * 64 * 2);
    unsigned short* Wf2 = (unsigned short*)take((size_t)RR * 64 * 64 * 2);
    unsigned short* Sf1 = (unsigned short*)take((size_t)128 * 16 * 2);
    unsigned short* Sf2 = (unsigned short*)take((size_t)64 * 16 * 2);
    unsigned short* xw  = (unsigned short*)take((size_t)RR * NN * 64 * 2);

    const int nb_part  = (EE + ACHUNK - 1) / ACHUNK;   // 196
    const int nb_agg   = NN / 4;                       // 25000
    const int nb_elem  = (NN * 64) / 256;

    prep<<<22, 256, 0, stream>>>(W1, q1, k1, W2, q2, k2, Wf1, Wf2, Sf1, Sf2,
                                 bcnt, stats);
    part_scatter<<<nb_part, 256, 0, stream>>>(src, dst, et, bcnt, tmp);
    bucket_csr<<<NBKT, 512, 0, stream>>>(bcnt, tmp, rowstart, rowdeg, pk);

    gemm_mfma<128, false><<<NB_NODES, 256, 0, stream>>>(x0, Wf1, Sf1, xw, sq, sk, gmax);
    max_reduce<<<1, 64, 0, stream>>>(gmax, mxk1);
    node_aggregate<1><<<nb_agg, 256, 0, stream>>>(rowstart, rowdeg, pk, sq, sk, mxk1,
                                                  xw, b1, x1);

    gemm_mfma<64, true><<<NB_NODES, 256, 0, stream>>>(x1, Wf2, Sf2, xw, sq, sk, gmax);
    max_reduce<<<1, 64, 0, stream>>>(gmax, mxk2);
    node_aggregate<2><<<nb_agg, 256, 0, stream>>>(rowstart, rowdeg, pk, sq, sk, mxk2,
                                                  xw, nullptr, out);

    bn_stats<<<512, 256, 0, stream>>>(out, stats);
    bn_apply<<<nb_elem, 256, 0, stream>>>(out, stats, gamma, beta);
}

// Round 5
// 422.264 us; speedup vs baseline: 1.1072x; 1.1072x over previous
//
#include <hip/hip_runtime.h>
#include <hip/hip_bf16.h>

#define NN 100000
#define EE 1600000
#define RR 8
#define NBKT 196          // ceil(NN/512) buckets of 512 nodes
#define ACHUNK 8192       // edges per partition block
#define CAP 10240         // per-bucket capacity: mean 8192, sd ~90 -> 22 sigma headroom
#define NB_NODES ((NN + 63) / 64)   // 1563 gemm blocks

typedef __attribute__((ext_vector_type(8))) short bf16x8;
typedef __attribute__((ext_vector_type(4))) float f32x4;

__device__ __forceinline__ unsigned short f2bf(float v) {
    __hip_bfloat16 h = __float2bfloat16(v);
    return *reinterpret_cast<unsigned short*>(&h);
}
__device__ __forceinline__ float bf2f(unsigned short u) {
    unsigned x = (unsigned)u << 16;
    return __uint_as_float(x);
}

// ---------- prep device helpers ----------
template<int IN_DIM>
__device__ __forceinline__ void wt_frag_dev(const float* __restrict__ W,
                                            unsigned short* __restrict__ Wf, int r) {
    constexpr int KSTEPS = IN_DIM / 32;
    for (int i = threadIdx.x; i < IN_DIM * 64; i += 256) {
        int k = i >> 6, o = i & 63;
        int ks = k >> 5, quad = (k >> 3) & 3, j = k & 7;
        int tl = o >> 4, l16 = o & 15;
        int lane = quad * 16 + l16;
        size_t idx = ((((size_t)r * KSTEPS + ks) * 4 + tl) * 64 + lane) * 8 + j;
        Wf[idx] = f2bf(W[((size_t)r * IN_DIM + k) * 64 + o]);
    }
}

template<int IN_DIM>
__device__ __forceinline__ void wqk_frag_dev(const float* __restrict__ W,
        const float* __restrict__ q, const float* __restrict__ k,
        unsigned short* __restrict__ Sf, int blk, int nb) {
    for (int i = blk * 256 + threadIdx.x; i < IN_DIM * 16; i += nb * 256) {
        int j = i & 7, lane = (i >> 3) & 63, ks = i >> 9;
        int col = lane & 15, quad = lane >> 4;
        int kd = ks * 32 + quad * 8 + j;
        const float* v = (col < 8) ? q : k;
        int r = (col < 8) ? col : col - 8;
        float s = 0.f;
        #pragma unroll
        for (int o = 0; o < 64; o++) s += W[((size_t)r * IN_DIM + kd) * 64 + o] * v[o];
        Sf[i] = f2bf(s);
    }
}

// one kernel: all weight prep + all zero-init
__global__ __launch_bounds__(256)
void prep(const float* __restrict__ W1, const float* __restrict__ q1, const float* __restrict__ k1,
          const float* __restrict__ W2, const float* __restrict__ q2, const float* __restrict__ k2,
          unsigned short* __restrict__ Wf1, unsigned short* __restrict__ Wf2,
          unsigned short* __restrict__ Sf1, unsigned short* __restrict__ Sf2,
          unsigned* __restrict__ bcnt, float* __restrict__ stats)
{
    int b = blockIdx.x;
    if (b < 8)        wt_frag_dev<128>(W1, Wf1, b);
    else if (b < 16)  wt_frag_dev<64>(W2, Wf2, b - 8);
    else if (b < 20)  wqk_frag_dev<128>(W1, q1, k1, Sf1, b - 16, 4);
    else if (b == 20) wqk_frag_dev<64>(W2, q2, k2, Sf2, 0, 1);
    else {
        int t = threadIdx.x;
        if (t < NBKT) bcnt[t] = 0;
        if (t < 128) stats[t] = 0.f;
    }
}

// ---------------- bucketed CSR build (single-pass: fixed-capacity buckets) ----------------
__global__ __launch_bounds__(256)
void part_scatter(const int* __restrict__ src, const int* __restrict__ dst,
                  const int* __restrict__ et, unsigned* __restrict__ bcnt,
                  unsigned* __restrict__ tmp) {
    __shared__ unsigned h[NBKT], base[NBKT];
    int t = threadIdx.x;
    for (int i = t; i < NBKT; i += 256) h[i] = 0;
    __syncthreads();
    int e0 = blockIdx.x * ACHUNK;
    for (int i = t; i < ACHUNK; i += 256) {
        int e = e0 + i;
        if (e < EE) atomicAdd(&h[((unsigned)dst[e]) >> 9], 1u);
    }
    __syncthreads();
    for (int i = t; i < NBKT; i += 256) {
        base[i] = (unsigned)i * CAP + (h[i] ? atomicAdd(&bcnt[i], h[i]) : 0u);
        h[i] = 0;
    }
    __syncthreads();
    for (int i = t; i < ACHUNK; i += 256) {
        int e = e0 + i;
        if (e < EE) {
            unsigned d = (unsigned)dst[e];
            unsigned bk = d >> 9;
            unsigned off = atomicAdd(&h[bk], 1u);
            unsigned pos = base[bk] + off;
            if (pos < (bk + 1u) * CAP) {   // statistically unreachable clamp
                unsigned val = ((d & 511u) << 23) | ((unsigned)et[e] << 20) | (unsigned)src[e];
                tmp[pos] = val;
            }
        }
    }
}

__global__ __launch_bounds__(512)
void bucket_csr(const unsigned* __restrict__ bcnt, const unsigned* __restrict__ tmp,
                unsigned* __restrict__ rowstart, unsigned* __restrict__ rowdeg,
                unsigned* __restrict__ pk) {
    __shared__ unsigned lcnt[512], lscan[512], lrs[512];
    int b = blockIdx.x, t = threadIdx.x;
    unsigned ebeg = (unsigned)b * CAP;
    unsigned cnt = min(bcnt[b], (unsigned)CAP);
    unsigned eend = ebeg + cnt;
    lcnt[t] = 0;
    __syncthreads();
    for (unsigned i = ebeg + t; i < eend; i += 512)
        atomicAdd(&lcnt[tmp[i] >> 23], 1u);
    __syncthreads();
    unsigned v = lcnt[t];
    lscan[t] = v;
    __syncthreads();
    for (int off = 1; off < 512; off <<= 1) {
        unsigned u = (t >= off) ? lscan[t - off] : 0u;
        __syncthreads();
        lscan[t] += u;
        __syncthreads();
    }
    unsigned excl = lscan[t] - v;
    lrs[t] = ebeg + excl;
    int node = b * 512 + t;
    if (node < NN) { rowstart[node] = ebeg + excl; rowdeg[node] = v; }
    lcnt[t] = 0;
    __syncthreads();
    for (unsigned i = ebeg + t; i < eend; i += 512) {
        unsigned val = tmp[i];
        unsigned d = val >> 23;
        unsigned pos = lrs[d] + atomicAdd(&lcnt[d], 1u);
        pk[pos] = val & 0x7FFFFFu;
    }
}

// ---------- MFMA GEMM: weights staged per-relation into LDS (R4 showed VGPR=32 ->
// compiler serialized the 16 weight loads at L2 latency; cooperative 256-thread
// staging + ds_read_b128 removes the exposed-latency chain) ----------
template<int IN_DIM, bool BF16IN>
__global__ __launch_bounds__(256)
void gemm_mfma(const void* __restrict__ xv, const unsigned short* __restrict__ Wf,
               const unsigned short* __restrict__ Sf,
               unsigned short* __restrict__ xw,
               float* __restrict__ sq, float* __restrict__ sk,
               float* __restrict__ gmax)
{
    constexpr int KSTEPS = IN_DIM / 32;
    constexpr int NB = IN_DIM / 8;
    constexpr int WITEMS = KSTEPS * 4 * 64;           // bf16x8 items per relation
    __shared__ alignas(16) unsigned short xl[64 * IN_DIM];
    __shared__ alignas(16) unsigned short wl[WITEMS * 8];   // 16KB (128) / 8KB (64)
    __shared__ float smax[4][8];

    const int n0 = blockIdx.x * 64;
    const int t = threadIdx.x;
    const int wave = t >> 6, lane = t & 63;
    const int quad = lane >> 4, l16 = lane & 15;

    for (int c = t; c < 64 * IN_DIM / 4; c += 256) {
        int row = c / (IN_DIM / 4), kc = (c % (IN_DIM / 4)) * 4;
        int gr = n0 + row;
        ushort4 u = make_ushort4(0, 0, 0, 0);
        if constexpr (BF16IN) {
            if (gr < NN) u = *(const ushort4*)((const unsigned short*)xv + (size_t)gr * IN_DIM + kc);
        } else {
            if (gr < NN) {
                float4 v = *(const float4*)((const float*)xv + (size_t)gr * IN_DIM + kc);
                u.x = f2bf(v.x); u.y = f2bf(v.y); u.z = f2bf(v.z); u.w = f2bf(v.w);
            }
        }
        int b = kc >> 3;
        *(ushort4*)&xl[row * IN_DIM + ((b ^ (row & (NB - 1))) << 3) + (kc & 7)] = u;
    }
    __syncthreads();

    bf16x8 afr[KSTEPS];
    const int arow = wave * 16 + l16;
    #pragma unroll
    for (int ks = 0; ks < KSTEPS; ks++) {
        int b = ks * 4 + quad;
        afr[ks] = *(const bf16x8*)&xl[arow * IN_DIM + ((b ^ (arow & (NB - 1))) << 3)];
    }

    // ---- sq/sk for ALL relations via one MFMA chain + per-block sk max ----
    {
        f32x4 accs = {0.f, 0.f, 0.f, 0.f};
        #pragma unroll
        for (int ks = 0; ks < KSTEPS; ks++) {
            bf16x8 sfr = *(const bf16x8*)&Sf[(ks * 64 + lane) * 8];
            accs = __builtin_amdgcn_mfma_f32_16x16x32_bf16(afr[ks], sfr, accs, 0, 0, 0);
        }
        float pm = -1e30f;
        #pragma unroll
        for (int reg = 0; reg < 4; reg++) {
            int grow = n0 + wave * 16 + quad * 4 + reg;
            if (grow < NN) {
                if (l16 < 8) sq[(size_t)l16 * NN + grow] = accs[reg];
                else { sk[(size_t)(l16 - 8) * NN + grow] = accs[reg]; pm = fmaxf(pm, accs[reg]); }
            }
        }
        pm = fmaxf(pm, __shfl_xor(pm, 16, 64));
        pm = fmaxf(pm, __shfl_xor(pm, 32, 64));
        if (quad == 0 && l16 >= 8) smax[wave][l16 - 8] = pm;
    }
    __syncthreads();
    if (t < 8) {
        float v = fmaxf(fmaxf(smax[0][t], smax[1][t]), fmaxf(smax[2][t], smax[3][t]));
        gmax[blockIdx.x * 8 + t] = v;                 // plain store, no RMW
    }

    #pragma unroll 1
    for (int r = 0; r < RR; r++) {
        // cooperative staging: 256 threads, 4 (128) / 2 (64) x 16B loads each,
        // coalesced + deeply pipelined (no per-wave L2-latency chain)
        const unsigned short* Wr = Wf + (size_t)r * WITEMS * 8;
        #pragma unroll
        for (int i = t; i < WITEMS; i += 256)
            *(bf16x8*)&wl[(size_t)i * 8] = *(const bf16x8*)(Wr + (size_t)i * 8);
        __syncthreads();

        bf16x8 bfr[KSTEPS][4];
        #pragma unroll
        for (int ks = 0; ks < KSTEPS; ks++)
            #pragma unroll
            for (int tl = 0; tl < 4; tl++)
                bfr[ks][tl] = *(const bf16x8*)&wl[(size_t)((ks * 4 + tl) * 64 + lane) * 8];

        f32x4 acc[4] = {{0.f,0.f,0.f,0.f},{0.f,0.f,0.f,0.f},{0.f,0.f,0.f,0.f},{0.f,0.f,0.f,0.f}};
        #pragma unroll
        for (int ks = 0; ks < KSTEPS; ks++)
            #pragma unroll
            for (int tl = 0; tl < 4; tl++)
                acc[tl] = __builtin_amdgcn_mfma_f32_16x16x32_bf16(afr[ks], bfr[ks][tl], acc[tl], 0, 0, 0);

        const size_t rbase = (size_t)r * NN;
        #pragma unroll
        for (int reg = 0; reg < 4; reg++) {
            int grow = n0 + wave * 16 + quad * 4 + reg;
            if (grow < NN) {
                ushort4 u;
                u.x = f2bf(acc[0][reg]); u.y = f2bf(acc[1][reg]);
                u.z = f2bf(acc[2][reg]); u.w = f2bf(acc[3][reg]);
                *(ushort4*)(xw + (rbase + grow) * 64 + l16 * 4) = u;
            }
        }
        __syncthreads();   // wl reads done before next relation's staging
    }
}

// ---------- parallel tree-reduce: gmax[1563][8] -> mxk[8]
// (R4 lesson: the 64-lane serial version was a 196-deep L2-latency chain ~20us;
//  256 threads x 4 independent accumulator chains => ~2us) ----------
__global__ __launch_bounds__(256)
void max_reduce(const float* __restrict__ gmax, float* __restrict__ mxk) {
    __shared__ float smr[32][8];
    int t = threadIdx.x;
    int r = t & 7, grp = t >> 3;                      // 32 groups of 8
    float m0 = -1e30f, m1 = -1e30f, m2 = -1e30f, m3 = -1e30f;
    for (int i = grp; i < NB_NODES; i += 128) {
        m0 = fmaxf(m0, gmax[i * 8 + r]);
        int i1 = i + 32, i2 = i + 64, i3 = i + 96;
        if (i1 < NB_NODES) m1 = fmaxf(m1, gmax[i1 * 8 + r]);
        if (i2 < NB_NODES) m2 = fmaxf(m2, gmax[i2 * 8 + r]);
        if (i3 < NB_NODES) m3 = fmaxf(m3, gmax[i3 * 8 + r]);
    }
    smr[grp][r] = fmaxf(fmaxf(m0, m1), fmaxf(m2, m3));
    __syncthreads();
    if (t < 8) {
        float mm = smr[0][t];
        #pragma unroll
        for (int g2 = 1; g2 < 32; g2++) mm = fmaxf(mm, smr[g2][t]);
        mxk[t] = mm;
    }
}

// ---------- Fused per-node softmax + aggregate ----------
// R0/R3-proven shfl-broadcast gather, 8 edges / 2 independent gathers in flight
// (pure registers — no LDS staging, no wave_barrier).
// sq held in lane (lane&7) and fetched per-edge via one shfl.
// LAYER==1 writes bf16 (gemm converts to bf16 anyway -> numerically identical).
template<int LAYER>
__global__ __launch_bounds__(256)
void node_aggregate(const unsigned* __restrict__ rowstart, const unsigned* __restrict__ rowdeg,
                    const unsigned* __restrict__ pk,
                    const float* __restrict__ sq, const float* __restrict__ sk,
                    const float* __restrict__ mxk,
                    const unsigned short* __restrict__ xw, const float* __restrict__ b,
                    void* __restrict__ outv)
{
    const int node = blockIdx.x * 4 + (threadIdx.x >> 6);
    const int lane = threadIdx.x & 63;
    const int g = lane >> 4, c16 = lane & 15;
    const unsigned beg = rowstart[node];
    const unsigned deg = rowdeg[node];
    const unsigned end = beg + deg;

    const float sqreg = sq[(size_t)(lane & 7) * NN + node];
    float tmx = sqreg + mxk[lane & 7];
    tmx = fmaxf(tmx, __shfl_xor(tmx, 1, 64));
    tmx = fmaxf(tmx, __shfl_xor(tmx, 2, 64));
    tmx = fmaxf(tmx, __shfl_xor(tmx, 4, 64));
    const float m = tmx > 0.f ? tmx : 0.2f * tmx;   // leaky is monotonic: bound survives

    float a0 = 0.f, a1 = 0.f, a2 = 0.f, a3 = 0.f, den = 0.f;
    for (unsigned c0 = beg; c0 < end; c0 += 64) {
        unsigned i = c0 + lane;
        unsigned p = 0;
        if (i < end) p = pk[i];
        unsigned r = p >> 20;
        unsigned rowidx = r * NN + (p & 0xFFFFFu);   // pads -> row 0 (harmless)
        float skv = sk[rowidx];
        float sqv_e = __shfl(sqreg, (int)r, 64);     // uniform flow: sources active
        float a = sqv_e + skv;
        a = a > 0.f ? a : 0.2f * a;
        float w = __expf(a - m);
        if (i >= end) w = 0.f;
        den += w;
        int cnt8 = ((int)min(64u, end - c0) + 7) & ~7;   // pad lanes have w=0
        for (int j = 0; j < cnt8; j += 8) {
            float    w0 = __shfl(w, j + g, 64);
            unsigned r0 = (unsigned)__shfl((int)rowidx, j + g, 64);
            float    w1 = __shfl(w, j + 4 + g, 64);
            unsigned r1 = (unsigned)__shfl((int)rowidx, j + 4 + g, 64);
            ushort4 v0 = *(const ushort4*)(xw + (size_t)r0 * 64 + c16 * 4);
            ushort4 v1 = *(const ushort4*)(xw + (size_t)r1 * 64 + c16 * 4);
            a0 += w0 * bf2f(v0.x) + w1 * bf2f(v1.x);
            a1 += w0 * bf2f(v0.y) + w1 * bf2f(v1.y);
            a2 += w0 * bf2f(v0.z) + w1 * bf2f(v1.z);
            a3 += w0 * bf2f(v0.w) + w1 * bf2f(v1.w);
        }
    }
    #pragma unroll
    for (int off = 32; off >= 1; off >>= 1)
        den += __shfl_xor(den, off, 64);
    // combine the 4 edge-subgroups: lanes L, L^16, L^32, L^48 hold same channels
    a0 += __shfl_xor(a0, 16, 64); a0 += __shfl_xor(a0, 32, 64);
    a1 += __shfl_xor(a1, 16, 64); a1 += __shfl_xor(a1, 32, 64);
    a2 += __shfl_xor(a2, 16, 64); a2 += __shfl_xor(a2, 32, 64);
    a3 += __shfl_xor(a3, 16, 64); a3 += __shfl_xor(a3, 32, 64);

    float accg = (g == 0) ? a0 : (g == 1) ? a1 : (g == 2) ? a2 : a3;
    float res = (deg > 0) ? accg / (den + 1e-16f) : 0.f;
    int c = g * 16 + c16;
    if constexpr (LAYER == 1) {
        res += b[c];
        res = res > 0.f ? res : 0.f;
        ((unsigned short*)outv)[(size_t)node * 64 + c] = f2bf(res);
    } else {
        ((float*)outv)[(size_t)node * 64 + c] = res;
    }
}

// ---------------- BatchNorm (separate stats kernel: 512 blocks -> 65k atomics, R0-proven) ----
__global__ __launch_bounds__(256)
void bn_stats(const float* __restrict__ x, float* __restrict__ stats)
{
    int c = threadIdx.x & 63;
    int w = threadIdx.x >> 6;
    float s = 0.f, s2 = 0.f;
    for (int row = blockIdx.x * 4 + w; row < NN; row += gridDim.x * 4) {
        float v = x[(size_t)row * 64 + c];
        s += v; s2 += v * v;
    }
    __shared__ float ls[4][64], ls2[4][64];
    ls[w][c] = s; ls2[w][c] = s2;
    __syncthreads();
    if (threadIdx.x < 64) {
        atomicAdd(&stats[c],      ls[0][c] + ls[1][c] + ls[2][c] + ls[3][c]);
        atomicAdd(&stats[64 + c], ls2[0][c] + ls2[1][c] + ls2[2][c] + ls2[3][c]);
    }
}

__global__ __launch_bounds__(256)
void bn_apply(float* __restrict__ x, const float* __restrict__ stats,
              const float* __restrict__ gamma, const float* __restrict__ beta)
{
    int i = blockIdx.x * 256 + threadIdx.x;
    if (i >= NN * 64) return;
    int c = i & 63;
    float mean = stats[c] * (1.f / NN);
    float var  = stats[64 + c] * (1.f / NN) - mean * mean;
    float sc   = rsqrtf(var + 1e-5f) * gamma[c];
    float v = (x[i] - mean) * sc + beta[c];
    x[i] = v > 0.f ? v : 0.01f * v;
}

// ---------------- driver ----------------
extern "C" void kernel_launch(void* const* d_in, const int* in_sizes, int n_in,
                              void* d_out, int out_size, void* d_ws, size_t ws_size,
                              hipStream_t stream)
{
    const float* x0 = (const float*)d_in[0];
    const int*   ei = (const int*)d_in[1];
    const int*   et = (const int*)d_in[2];
    const float* W1 = (const float*)d_in[3];
    const float* q1 = (const float*)d_in[4];
    const float* k1 = (const float*)d_in[5];
    const float* b1 = (const float*)d_in[6];
    const float* W2 = (const float*)d_in[7];
    const float* q2 = (const float*)d_in[8];
    const float* k2 = (const float*)d_in[9];
    const float* gamma = (const float*)d_in[11];
    const float* beta  = (const float*)d_in[12];
    const int* src = ei;
    const int* dst = ei + EE;
    float* out = (float*)d_out;

    char* base = (char*)d_ws;
    size_t off = 0;
    auto take = [&](size_t bytes) -> char* {
        char* p = base + off;
        off = (off + bytes + 255) & ~(size_t)255;
        return p;
    };
    float*    sq       = (float*)take((size_t)RR * NN * 4);
    float*    sk       = (float*)take((size_t)RR * NN * 4);
    unsigned* rowstart = (unsigned*)take((size_t)NN * 4);
    unsigned* rowdeg   = (unsigned*)take((size_t)NN * 4);
    unsigned* bcnt     = (unsigned*)take((size_t)NBKT * 4);
    unsigned* tmp      = (unsigned*)take((size_t)NBKT * CAP * 4);
    unsigned* pk       = (unsigned*)take((size_t)NBKT * CAP * 4);
    unsigned short* x1 = (unsigned short*)take((size_t)NN * 64 * 2);
    float*    stats    = (float*)take(512);
    float*    gmax     = (float*)take((size_t)NB_NODES * 8 * 4);
    float*    mxk1     = (float*)take(RR * 4);
    float*    mxk2     = (float*)take(RR * 4);
    unsigned short* Wf1 = (unsigned short*)take((size_t)RR * 128 * 64 * 2);
    unsigned short* Wf2 = (unsigned short*)take((size_t)RR * 64 * 64 * 2);
    unsigned short* Sf1 = (unsigned short*)take((size_t)128 * 16 * 2);
    unsigned short* Sf2 = (unsigned short*)take((size_t)64 * 16 * 2);
    unsigned short* xw  = (unsigned short*)take((size_t)RR * NN * 64 * 2);

    const int nb_part  = (EE + ACHUNK - 1) / ACHUNK;   // 196
    const int nb_agg   = NN / 4;                       // 25000
    const int nb_elem  = (NN * 64) / 256;

    prep<<<22, 256, 0, stream>>>(W1, q1, k1, W2, q2, k2, Wf1, Wf2, Sf1, Sf2,
                                 bcnt, stats);
    part_scatter<<<nb_part, 256, 0, stream>>>(src, dst, et, bcnt, tmp);
    bucket_csr<<<NBKT, 512, 0, stream>>>(bcnt, tmp, rowstart, rowdeg, pk);

    gemm_mfma<128, false><<<NB_NODES, 256, 0, stream>>>(x0, Wf1, Sf1, xw, sq, sk, gmax);
    max_reduce<<<1, 256, 0, stream>>>(gmax, mxk1);
    node_aggregate<1><<<nb_agg, 256, 0, stream>>>(rowstart, rowdeg, pk, sq, sk, mxk1,
                                                  xw, b1, x1);

    gemm_mfma<64, true><<<NB_NODES, 256, 0, stream>>>(x1, Wf2, Sf2, xw, sq, sk, gmax);
    max_reduce<<<1, 256, 0, stream>>>(gmax, mxk2);
    node_aggregate<2><<<nb_agg, 256, 0, stream>>>(rowstart, rowdeg, pk, sq, sk, mxk2,
                                                  xw, nullptr, out);

    bn_stats<<<512, 256, 0, stream>>>(out, stats);
    bn_apply<<<nb_elem, 256, 0, stream>>>(out, stats, gamma, beta);
}

// Round 6
// 420.344 us; speedup vs baseline: 1.1123x; 1.0046x over previous
//
#include <hip/hip_runtime.h>
#include <hip/hip_bf16.h>

#define NN 100000
#define EE 1600000
#define RR 8
#define NBKT 196          // ceil(NN/512) buckets of 512 nodes
#define ACHUNK 8192       // edges per partition block
#define CAP 10240         // per-bucket capacity: mean 8192, sd ~90 -> 22 sigma headroom
#define NB_NODES ((NN + 63) / 64)   // 1563 gemm blocks

typedef __attribute__((ext_vector_type(8))) short bf16x8;
typedef __attribute__((ext_vector_type(4))) float f32x4;

__device__ __forceinline__ unsigned short f2bf(float v) {
    __hip_bfloat16 h = __float2bfloat16(v);
    return *reinterpret_cast<unsigned short*>(&h);
}
__device__ __forceinline__ float bf2f(unsigned short u) {
    unsigned x = (unsigned)u << 16;
    return __uint_as_float(x);
}
__device__ __forceinline__ float bflo(unsigned u) {   // low bf16 of packed dword
    return __uint_as_float(u << 16);
}
__device__ __forceinline__ float bfhi(unsigned u) {   // high bf16 of packed dword
    return __uint_as_float(u & 0xFFFF0000u);
}

// ---------- prep device helpers ----------
template<int IN_DIM>
__device__ __forceinline__ void wt_frag_dev(const float* __restrict__ W,
                                            unsigned short* __restrict__ Wf, int r) {
    constexpr int KSTEPS = IN_DIM / 32;
    for (int i = threadIdx.x; i < IN_DIM * 64; i += 256) {
        int k = i >> 6, o = i & 63;
        int ks = k >> 5, quad = (k >> 3) & 3, j = k & 7;
        int tl = o >> 4, l16 = o & 15;
        int lane = quad * 16 + l16;
        size_t idx = ((((size_t)r * KSTEPS + ks) * 4 + tl) * 64 + lane) * 8 + j;
        Wf[idx] = f2bf(W[((size_t)r * IN_DIM + k) * 64 + o]);
    }
}

template<int IN_DIM>
__device__ __forceinline__ void wqk_frag_dev(const float* __restrict__ W,
        const float* __restrict__ q, const float* __restrict__ k,
        unsigned short* __restrict__ Sf, int blk, int nb) {
    for (int i = blk * 256 + threadIdx.x; i < IN_DIM * 16; i += nb * 256) {
        int j = i & 7, lane = (i >> 3) & 63, ks = i >> 9;
        int col = lane & 15, quad = lane >> 4;
        int kd = ks * 32 + quad * 8 + j;
        const float* v = (col < 8) ? q : k;
        int r = (col < 8) ? col : col - 8;
        float s = 0.f;
        #pragma unroll
        for (int o = 0; o < 64; o++) s += W[((size_t)r * IN_DIM + kd) * 64 + o] * v[o];
        Sf[i] = f2bf(s);
    }
}

// one kernel: all weight prep + all zero-init
__global__ __launch_bounds__(256)
void prep(const float* __restrict__ W1, const float* __restrict__ q1, const float* __restrict__ k1,
          const float* __restrict__ W2, const float* __restrict__ q2, const float* __restrict__ k2,
          unsigned short* __restrict__ Wf1, unsigned short* __restrict__ Wf2,
          unsigned short* __restrict__ Sf1, unsigned short* __restrict__ Sf2,
          unsigned* __restrict__ bcnt, float* __restrict__ stats)
{
    int b = blockIdx.x;
    if (b < 8)        wt_frag_dev<128>(W1, Wf1, b);
    else if (b < 16)  wt_frag_dev<64>(W2, Wf2, b - 8);
    else if (b < 20)  wqk_frag_dev<128>(W1, q1, k1, Sf1, b - 16, 4);
    else if (b == 20) wqk_frag_dev<64>(W2, q2, k2, Sf2, 0, 1);
    else {
        int t = threadIdx.x;
        if (t < NBKT) bcnt[t] = 0;
        if (t < 128) stats[t] = 0.f;
    }
}

// ---------------- bucketed CSR build (single-pass: fixed-capacity buckets) ----------------
__global__ __launch_bounds__(256)
void part_scatter(const int* __restrict__ src, const int* __restrict__ dst,
                  const int* __restrict__ et, unsigned* __restrict__ bcnt,
                  unsigned* __restrict__ tmp) {
    __shared__ unsigned h[NBKT], base[NBKT];
    int t = threadIdx.x;
    for (int i = t; i < NBKT; i += 256) h[i] = 0;
    __syncthreads();
    int e0 = blockIdx.x * ACHUNK;
    for (int i = t; i < ACHUNK; i += 256) {
        int e = e0 + i;
        if (e < EE) atomicAdd(&h[((unsigned)dst[e]) >> 9], 1u);
    }
    __syncthreads();
    for (int i = t; i < NBKT; i += 256) {
        base[i] = (unsigned)i * CAP + (h[i] ? atomicAdd(&bcnt[i], h[i]) : 0u);
        h[i] = 0;
    }
    __syncthreads();
    for (int i = t; i < ACHUNK; i += 256) {
        int e = e0 + i;
        if (e < EE) {
            unsigned d = (unsigned)dst[e];
            unsigned bk = d >> 9;
            unsigned off = atomicAdd(&h[bk], 1u);
            unsigned pos = base[bk] + off;
            if (pos < (bk + 1u) * CAP) {   // statistically unreachable clamp
                unsigned val = ((d & 511u) << 23) | ((unsigned)et[e] << 20) | (unsigned)src[e];
                tmp[pos] = val;
            }
        }
    }
}

__global__ __launch_bounds__(512)
void bucket_csr(const unsigned* __restrict__ bcnt, const unsigned* __restrict__ tmp,
                unsigned* __restrict__ rowstart, unsigned* __restrict__ rowdeg,
                unsigned* __restrict__ pk) {
    __shared__ unsigned lcnt[512], lscan[512], lrs[512];
    int b = blockIdx.x, t = threadIdx.x;
    unsigned ebeg = (unsigned)b * CAP;
    unsigned cnt = min(bcnt[b], (unsigned)CAP);
    unsigned eend = ebeg + cnt;
    lcnt[t] = 0;
    __syncthreads();
    for (unsigned i = ebeg + t; i < eend; i += 512)
        atomicAdd(&lcnt[tmp[i] >> 23], 1u);
    __syncthreads();
    unsigned v = lcnt[t];
    lscan[t] = v;
    __syncthreads();
    for (int off = 1; off < 512; off <<= 1) {
        unsigned u = (t >= off) ? lscan[t - off] : 0u;
        __syncthreads();
        lscan[t] += u;
        __syncthreads();
    }
    unsigned excl = lscan[t] - v;
    lrs[t] = ebeg + excl;
    int node = b * 512 + t;
    if (node < NN) { rowstart[node] = ebeg + excl; rowdeg[node] = v; }
    lcnt[t] = 0;
    __syncthreads();
    for (unsigned i = ebeg + t; i < eend; i += 512) {
        unsigned val = tmp[i];
        unsigned d = val >> 23;
        unsigned pos = lrs[d] + atomicAdd(&lcnt[d], 1u);
        pk[pos] = val & 0x7FFFFFu;
    }
}

// ---------- MFMA GEMM: weights staged per-relation into LDS (R5-proven) ----------
template<int IN_DIM, bool BF16IN>
__global__ __launch_bounds__(256)
void gemm_mfma(const void* __restrict__ xv, const unsigned short* __restrict__ Wf,
               const unsigned short* __restrict__ Sf,
               unsigned short* __restrict__ xw,
               float* __restrict__ sq, float* __restrict__ sk,
               float* __restrict__ gmax)
{
    constexpr int KSTEPS = IN_DIM / 32;
    constexpr int NB = IN_DIM / 8;
    constexpr int WITEMS = KSTEPS * 4 * 64;           // bf16x8 items per relation
    __shared__ alignas(16) unsigned short xl[64 * IN_DIM];
    __shared__ alignas(16) unsigned short wl[WITEMS * 8];   // 16KB (128) / 8KB (64)
    __shared__ float smax[4][8];

    const int n0 = blockIdx.x * 64;
    const int t = threadIdx.x;
    const int wave = t >> 6, lane = t & 63;
    const int quad = lane >> 4, l16 = lane & 15;

    for (int c = t; c < 64 * IN_DIM / 4; c += 256) {
        int row = c / (IN_DIM / 4), kc = (c % (IN_DIM / 4)) * 4;
        int gr = n0 + row;
        ushort4 u = make_ushort4(0, 0, 0, 0);
        if constexpr (BF16IN) {
            if (gr < NN) u = *(const ushort4*)((const unsigned short*)xv + (size_t)gr * IN_DIM + kc);
        } else {
            if (gr < NN) {
                float4 v = *(const float4*)((const float*)xv + (size_t)gr * IN_DIM + kc);
                u.x = f2bf(v.x); u.y = f2bf(v.y); u.z = f2bf(v.z); u.w = f2bf(v.w);
            }
        }
        int b = kc >> 3;
        *(ushort4*)&xl[row * IN_DIM + ((b ^ (row & (NB - 1))) << 3) + (kc & 7)] = u;
    }
    __syncthreads();

    bf16x8 afr[KSTEPS];
    const int arow = wave * 16 + l16;
    #pragma unroll
    for (int ks = 0; ks < KSTEPS; ks++) {
        int b = ks * 4 + quad;
        afr[ks] = *(const bf16x8*)&xl[arow * IN_DIM + ((b ^ (arow & (NB - 1))) << 3)];
    }

    // ---- sq/sk for ALL relations via one MFMA chain + per-block sk max ----
    {
        f32x4 accs = {0.f, 0.f, 0.f, 0.f};
        #pragma unroll
        for (int ks = 0; ks < KSTEPS; ks++) {
            bf16x8 sfr = *(const bf16x8*)&Sf[(ks * 64 + lane) * 8];
            accs = __builtin_amdgcn_mfma_f32_16x16x32_bf16(afr[ks], sfr, accs, 0, 0, 0);
        }
        float pm = -1e30f;
        #pragma unroll
        for (int reg = 0; reg < 4; reg++) {
            int grow = n0 + wave * 16 + quad * 4 + reg;
            if (grow < NN) {
                if (l16 < 8) sq[(size_t)l16 * NN + grow] = accs[reg];
                else { sk[(size_t)(l16 - 8) * NN + grow] = accs[reg]; pm = fmaxf(pm, accs[reg]); }
            }
        }
        pm = fmaxf(pm, __shfl_xor(pm, 16, 64));
        pm = fmaxf(pm, __shfl_xor(pm, 32, 64));
        if (quad == 0 && l16 >= 8) smax[wave][l16 - 8] = pm;
    }
    __syncthreads();
    if (t < 8) {
        float v = fmaxf(fmaxf(smax[0][t], smax[1][t]), fmaxf(smax[2][t], smax[3][t]));
        gmax[blockIdx.x * 8 + t] = v;                 // plain store, no RMW
    }

    #pragma unroll 1
    for (int r = 0; r < RR; r++) {
        // cooperative staging: 256 threads, coalesced 16B loads, deeply pipelined
        const unsigned short* Wr = Wf + (size_t)r * WITEMS * 8;
        #pragma unroll
        for (int i = t; i < WITEMS; i += 256)
            *(bf16x8*)&wl[(size_t)i * 8] = *(const bf16x8*)(Wr + (size_t)i * 8);
        __syncthreads();

        bf16x8 bfr[KSTEPS][4];
        #pragma unroll
        for (int ks = 0; ks < KSTEPS; ks++)
            #pragma unroll
            for (int tl = 0; tl < 4; tl++)
                bfr[ks][tl] = *(const bf16x8*)&wl[(size_t)((ks * 4 + tl) * 64 + lane) * 8];

        f32x4 acc[4] = {{0.f,0.f,0.f,0.f},{0.f,0.f,0.f,0.f},{0.f,0.f,0.f,0.f},{0.f,0.f,0.f,0.f}};
        #pragma unroll
        for (int ks = 0; ks < KSTEPS; ks++)
            #pragma unroll
            for (int tl = 0; tl < 4; tl++)
                acc[tl] = __builtin_amdgcn_mfma_f32_16x16x32_bf16(afr[ks], bfr[ks][tl], acc[tl], 0, 0, 0);

        const size_t rbase = (size_t)r * NN;
        #pragma unroll
        for (int reg = 0; reg < 4; reg++) {
            int grow = n0 + wave * 16 + quad * 4 + reg;
            if (grow < NN) {
                ushort4 u;
                u.x = f2bf(acc[0][reg]); u.y = f2bf(acc[1][reg]);
                u.z = f2bf(acc[2][reg]); u.w = f2bf(acc[3][reg]);
                *(ushort4*)(xw + (rbase + grow) * 64 + l16 * 4) = u;
            }
        }
        __syncthreads();   // wl reads done before next relation's staging
    }
}

// ---------- parallel tree-reduce: gmax[1563][8] -> mxk[8] (R5-proven) ----------
__global__ __launch_bounds__(256)
void max_reduce(const float* __restrict__ gmax, float* __restrict__ mxk) {
    __shared__ float smr[32][8];
    int t = threadIdx.x;
    int r = t & 7, grp = t >> 3;                      // 32 groups of 8
    float m0 = -1e30f, m1 = -1e30f, m2 = -1e30f, m3 = -1e30f;
    for (int i = grp; i < NB_NODES; i += 128) {
        m0 = fmaxf(m0, gmax[i * 8 + r]);
        int i1 = i + 32, i2 = i + 64, i3 = i + 96;
        if (i1 < NB_NODES) m1 = fmaxf(m1, gmax[i1 * 8 + r]);
        if (i2 < NB_NODES) m2 = fmaxf(m2, gmax[i2 * 8 + r]);
        if (i3 < NB_NODES) m3 = fmaxf(m3, gmax[i3 * 8 + r]);
    }
    smr[grp][r] = fmaxf(fmaxf(m0, m1), fmaxf(m2, m3));
    __syncthreads();
    if (t < 8) {
        float mm = smr[0][t];
        #pragma unroll
        for (int g2 = 1; g2 < 32; g2++) mm = fmaxf(mm, smr[g2][t]);
        mxk[t] = mm;
    }
}

// ---------- Fused per-node softmax + aggregate ----------
// Gather restructured for memory-level parallelism (R5: 51% BW, latency-bound):
// 8 groups of 8 lanes; each lane reads a FULL 16B (uint4 = 8 packed bf16) of one
// edge's xw row -> 2x16B in flight per lane (was 2x8B), half the load+shfl instrs.
// Position->channel map: ch(p) = (p&3)*16 + (p>>2); lane c8 reads p = c8*8+s so
// acc s holds ch (s&3)*16 + c8*2 + (s>>2); resolved at the final write.
// Pure registers + shfl: no LDS staging, no atomics (R1/R2 lessons).
template<int LAYER>
__global__ __launch_bounds__(256)
void node_aggregate(const unsigned* __restrict__ rowstart, const unsigned* __restrict__ rowdeg,
                    const unsigned* __restrict__ pk,
                    const float* __restrict__ sq, const float* __restrict__ sk,
                    const float* __restrict__ mxk,
                    const unsigned short* __restrict__ xw, const float* __restrict__ b,
                    void* __restrict__ outv)
{
    const int node = blockIdx.x * 4 + (threadIdx.x >> 6);
    const int lane = threadIdx.x & 63;
    const int g = lane >> 3, c8 = lane & 7;
    const unsigned beg = rowstart[node];
    const unsigned deg = rowdeg[node];
    const unsigned end = beg + deg;

    const float sqreg = sq[(size_t)c8 * NN + node];
    float tmx = sqreg + mxk[c8];
    tmx = fmaxf(tmx, __shfl_xor(tmx, 1, 64));
    tmx = fmaxf(tmx, __shfl_xor(tmx, 2, 64));
    tmx = fmaxf(tmx, __shfl_xor(tmx, 4, 64));
    const float m = tmx > 0.f ? tmx : 0.2f * tmx;   // leaky is monotonic: bound survives

    float a0 = 0.f, a1 = 0.f, a2 = 0.f, a3 = 0.f;
    float a4 = 0.f, a5 = 0.f, a6 = 0.f, a7 = 0.f, den = 0.f;
    for (unsigned c0 = beg; c0 < end; c0 += 64) {
        unsigned i = c0 + lane;
        unsigned p = 0;
        if (i < end) p = pk[i];
        unsigned r = p >> 20;
        unsigned rowidx = r * NN + (p & 0xFFFFFu);   // pads -> row 0 (harmless)
        float skv = sk[rowidx];
        float sqv_e = __shfl(sqreg, (int)r, 64);     // uniform flow: sources active
        float a = sqv_e + skv;
        a = a > 0.f ? a : 0.2f * a;
        float w = __expf(a - m);
        if (i >= end) w = 0.f;
        den += w;
        int cnt16 = ((int)min(64u, end - c0) + 15) & ~15;   // pad lanes have w=0
        for (int j = 0; j < cnt16; j += 16) {
            float    w0 = __shfl(w, j + g, 64);
            unsigned r0 = (unsigned)__shfl((int)rowidx, j + g, 64);
            float    w1 = __shfl(w, j + 8 + g, 64);
            unsigned r1 = (unsigned)__shfl((int)rowidx, j + 8 + g, 64);
            uint4 q0 = *(const uint4*)(xw + (size_t)r0 * 64 + c8 * 8);
            uint4 q1 = *(const uint4*)(xw + (size_t)r1 * 64 + c8 * 8);
            a0 += w0 * bflo(q0.x) + w1 * bflo(q1.x);
            a1 += w0 * bfhi(q0.x) + w1 * bfhi(q1.x);
            a2 += w0 * bflo(q0.y) + w1 * bflo(q1.y);
            a3 += w0 * bfhi(q0.y) + w1 * bfhi(q1.y);
            a4 += w0 * bflo(q0.z) + w1 * bflo(q1.z);
            a5 += w0 * bfhi(q0.z) + w1 * bfhi(q1.z);
            a6 += w0 * bflo(q0.w) + w1 * bflo(q1.w);
            a7 += w0 * bfhi(q0.w) + w1 * bfhi(q1.w);
        }
    }
    #pragma unroll
    for (int off = 32; off >= 1; off >>= 1)
        den += __shfl_xor(den, off, 64);
    // combine the 8 edge-subgroups (lane bits 3,4,5)
    a0 += __shfl_xor(a0, 8, 64); a0 += __shfl_xor(a0, 16, 64); a0 += __shfl_xor(a0, 32, 64);
    a1 += __shfl_xor(a1, 8, 64); a1 += __shfl_xor(a1, 16, 64); a1 += __shfl_xor(a1, 32, 64);
    a2 += __shfl_xor(a2, 8, 64); a2 += __shfl_xor(a2, 16, 64); a2 += __shfl_xor(a2, 32, 64);
    a3 += __shfl_xor(a3, 8, 64); a3 += __shfl_xor(a3, 16, 64); a3 += __shfl_xor(a3, 32, 64);
    a4 += __shfl_xor(a4, 8, 64); a4 += __shfl_xor(a4, 16, 64); a4 += __shfl_xor(a4, 32, 64);
    a5 += __shfl_xor(a5, 8, 64); a5 += __shfl_xor(a5, 16, 64); a5 += __shfl_xor(a5, 32, 64);
    a6 += __shfl_xor(a6, 8, 64); a6 += __shfl_xor(a6, 16, 64); a6 += __shfl_xor(a6, 32, 64);
    a7 += __shfl_xor(a7, 8, 64); a7 += __shfl_xor(a7, 16, 64); a7 += __shfl_xor(a7, 32, 64);

    if (lane < 8) {
        const float inv = (deg > 0) ? 1.f / (den + 1e-16f) : 0.f;
        // acc s -> channel (s&3)*16 + c8*2 + (s>>2): group grp holds pair (a[grp], a[grp+4])
        float ev[4] = {a0, a1, a2, a3};
        float od[4] = {a4, a5, a6, a7};
        #pragma unroll
        for (int grp = 0; grp < 4; grp++) {
            int c = grp * 16 + c8 * 2;
            float v0 = ev[grp] * inv;
            float v1 = od[grp] * inv;
            if constexpr (LAYER == 1) {
                v0 += b[c];     v1 += b[c + 1];
                v0 = v0 > 0.f ? v0 : 0.f;
                v1 = v1 > 0.f ? v1 : 0.f;
                unsigned pk2 = (unsigned)f2bf(v0) | ((unsigned)f2bf(v1) << 16);
                *(unsigned*)((unsigned short*)outv + (size_t)node * 64 + c) = pk2;
            } else {
                *(float2*)((float*)outv + (size_t)node * 64 + c) = make_float2(v0, v1);
            }
        }
    }
}

// ---------------- BatchNorm (separate stats kernel: 512 blocks -> 65k atomics, R0-proven) ----
__global__ __launch_bounds__(256)
void bn_stats(const float* __restrict__ x, float* __restrict__ stats)
{
    int c = threadIdx.x & 63;
    int w = threadIdx.x >> 6;
    float s = 0.f, s2 = 0.f;
    for (int row = blockIdx.x * 4 + w; row < NN; row += gridDim.x * 4) {
        float v = x[(size_t)row * 64 + c];
        s += v; s2 += v * v;
    }
    __shared__ float ls[4][64], ls2[4][64];
    ls[w][c] = s; ls2[w][c] = s2;
    __syncthreads();
    if (threadIdx.x < 64) {
        atomicAdd(&stats[c],      ls[0][c] + ls[1][c] + ls[2][c] + ls[3][c]);
        atomicAdd(&stats[64 + c], ls2[0][c] + ls2[1][c] + ls2[2][c] + ls2[3][c]);
    }
}

__global__ __launch_bounds__(256)
void bn_apply(float* __restrict__ x, const float* __restrict__ stats,
              const float* __restrict__ gamma, const float* __restrict__ beta)
{
    int i = blockIdx.x * 256 + threadIdx.x;
    if (i >= NN * 64) return;
    int c = i & 63;
    float mean = stats[c] * (1.f / NN);
    float var  = stats[64 + c] * (1.f / NN) - mean * mean;
    float sc   = rsqrtf(var + 1e-5f) * gamma[c];
    float v = (x[i] - mean) * sc + beta[c];
    x[i] = v > 0.f ? v : 0.01f * v;
}

// ---------------- driver ----------------
extern "C" void kernel_launch(void* const* d_in, const int* in_sizes, int n_in,
                              void* d_out, int out_size, void* d_ws, size_t ws_size,
                              hipStream_t stream)
{
    const float* x0 = (const float*)d_in[0];
    const int*   ei = (const int*)d_in[1];
    const int*   et = (const int*)d_in[2];
    const float* W1 = (const float*)d_in[3];
    const float* q1 = (const float*)d_in[4];
    const float* k1 = (const float*)d_in[5];
    const float* b1 = (const float*)d_in[6];
    const float* W2 = (const float*)d_in[7];
    const float* q2 = (const float*)d_in[8];
    const float* k2 = (const float*)d_in[9];
    const float* gamma = (const float*)d_in[11];
    const float* beta  = (const float*)d_in[12];
    const int* src = ei;
    const int* dst = ei + EE;
    float* out = (float*)d_out;

    char* base = (char*)d_ws;
    size_t off = 0;
    auto take = [&](size_t bytes) -> char* {
        char* p = base + off;
        off = (off + bytes + 255) & ~(size_t)255;
        return p;
    };
    float*    sq       = (float*)take((size_t)RR * NN * 4);
    float*    sk       = (float*)take((size_t)RR * NN * 4);
    unsigned* rowstart = (unsigned*)take((size_t)NN * 4);
    unsigned* rowdeg   = (unsigned*)take((size_t)NN * 4);
    unsigned* bcnt     = (unsigned*)take((size_t)NBKT * 4);
    unsigned* tmp      = (unsigned*)take((size_t)NBKT * CAP * 4);
    unsigned* pk       = (unsigned*)take((size_t)NBKT * CAP * 4);
    unsigned short* x1 = (unsigned short*)take((size_t)NN * 64 * 2);
    float*    stats    = (float*)take(512);
    float*    gmax     = (float*)take((size_t)NB_NODES * 8 * 4);
    float*    mxk1     = (float*)take(RR * 4);
    float*    mxk2     = (float*)take(RR * 4);
    unsigned short* Wf1 = (unsigned short*)take((size_t)RR * 128 * 64 * 2);
    unsigned short* Wf2 = (unsigned short*)take((size_t)RR * 64 * 64 * 2);
    unsigned short* Sf1 = (unsigned short*)take((size_t)128 * 16 * 2);
    unsigned short* Sf2 = (unsigned short*)take((size_t)64 * 16 * 2);
    unsigned short* xw  = (unsigned short*)take((size_t)RR * NN * 64 * 2);

    const int nb_part  = (EE + ACHUNK - 1) / ACHUNK;   // 196
    const int nb_agg   = NN / 4;                       // 25000
    const int nb_elem  = (NN * 64) / 256;

    prep<<<22, 256, 0, stream>>>(W1, q1, k1, W2, q2, k2, Wf1, Wf2, Sf1, Sf2,
                                 bcnt, stats);
    part_scatter<<<nb_part, 256, 0, stream>>>(src, dst, et, bcnt, tmp);
    bucket_csr<<<NBKT, 512, 0, stream>>>(bcnt, tmp, rowstart, rowdeg, pk);

    gemm_mfma<128, false><<<NB_NODES, 256, 0, stream>>>(x0, Wf1, Sf1, xw, sq, sk, gmax);
    max_reduce<<<1, 256, 0, stream>>>(gmax, mxk1);
    node_aggregate<1><<<nb_agg, 256, 0, stream>>>(rowstart, rowdeg, pk, sq, sk, mxk1,
                                                  xw, b1, x1);

    gemm_mfma<64, true><<<NB_NODES, 256, 0, stream>>>(x1, Wf2, Sf2, xw, sq, sk, gmax);
    max_reduce<<<1, 256, 0, stream>>>(gmax, mxk2);
    node_aggregate<2><<<nb_agg, 256, 0, stream>>>(rowstart, rowdeg, pk, sq, sk, mxk2,
                                                  xw, nullptr, out);

    bn_stats<<<512, 256, 0, stream>>>(out, stats);
    bn_apply<<<nb_elem, 256, 0, stream>>>(out, stats, gamma, beta);
}